// Round 1
// baseline (566.090 us; speedup 1.0000x reference)
//
#include <hip/hip_runtime.h>
#include <hip/hip_bf16.h>
#include <math.h>

// Problem constants (B,T,C,H) = (4,4096,256,64)
#define Bb   4
#define T    4096
#define Cc   256
#define Hh   64
#define BT   (Bb*T)          // 16384 rows
#define NQT  (T/64)          // 64 q-tiles of 64 rows
#define NSEG 4               // k-range split into 4 segments of 1024
#define SEG_TILES 16         // 16 k-tiles of 64 per segment

// ---------------------------------------------------------------------------
// Projection: q/k/v[row][h] = sum_c x[row][c] * W[c][h]
// grid = BT/64 = 256 blocks, 192 threads (3 waves: one per matrix)
// ---------------------------------------------------------------------------
__global__ __launch_bounds__(192) void proj_kernel(
    const float* __restrict__ x,
    const float* __restrict__ Wk, const float* __restrict__ Wq,
    const float* __restrict__ Wv,
    float* __restrict__ qo, float* __restrict__ ko, float* __restrict__ vo)
{
    __shared__ float xs[Cc][64];          // transposed x tile: xs[c][r], 64 KB
    const int t = threadIdx.x;
    const long rowbase = (long)blockIdx.x * 64;   // flattened (b*T + t) row

    // stage 64 rows x 256 c, transposed. 4096 float4 reads, coalesced.
    for (int idx = t; idx < 64 * (Cc/4); idx += 192) {
        const int r  = idx / (Cc/4);
        const int c4 = idx % (Cc/4);
        const float4 xv = ((const float4*)x)[rowbase*(Cc/4) + r*(Cc/4) + c4];
        xs[c4*4+0][r] = xv.x; xs[c4*4+1][r] = xv.y;
        xs[c4*4+2][r] = xv.z; xs[c4*4+3][r] = xv.w;
    }
    __syncthreads();

    const int h = t & 63;
    const int m = t >> 6;                 // 0=q 1=k 2=v
    const float* W   = (m == 0) ? Wq : (m == 1) ? Wk : Wv;
    float*       out = (m == 0) ? qo : (m == 1) ? ko : vo;

    for (int r0 = 0; r0 < 64; r0 += 16) {
        float acc[16];
        #pragma unroll
        for (int i = 0; i < 16; ++i) acc[i] = 0.f;
        #pragma unroll 4
        for (int c = 0; c < Cc; ++c) {
            const float w = W[c*Hh + h];
            const float4* xr = (const float4*)&xs[c][r0];   // broadcast reads
            #pragma unroll
            for (int j = 0; j < 4; ++j) {
                const float4 xv = xr[j];
                acc[j*4+0] += xv.x * w; acc[j*4+1] += xv.y * w;
                acc[j*4+2] += xv.z * w; acc[j*4+3] += xv.w * w;
            }
        }
        #pragma unroll
        for (int i = 0; i < 16; ++i)
            out[(rowbase + r0 + i)*Hh + h] = acc[i];
    }
}

// ---------------------------------------------------------------------------
// Flash attention partial over one k-segment.
// grid = Bb*NQT*NSEG = 1024 blocks, 256 threads.
// thread t: q-row = t>>2 (64 rows/block), sub = t&3 (16 h-elems each)
// ---------------------------------------------------------------------------
__global__ __launch_bounds__(256) void attn_partial(
    const float* __restrict__ q, const float* __restrict__ k,
    const float* __restrict__ v,
    float* __restrict__ part_o, float* __restrict__ part_ml)
{
    const int bid = blockIdx.x;           // = ((b*NQT)+qt)*NSEG + s
    const int s   = bid & (NSEG-1);
    const int qt  = (bid >> 2) & (NQT-1);
    const int b   = bid >> 8;
    const int kt0 = s * SEG_TILES;
    if (kt0 > qt) return;                 // fully masked segment
    const int kt1 = min(qt, kt0 + SEG_TILES - 1);

    __shared__ float kls[64][64];
    __shared__ float vls[64][64];

    const int t   = threadIdx.x;
    const int row = t >> 2;
    const int sub = t & 3;
    const long qg = (long)qt*64 + row;    // q index within batch

    // q fragment: 16 h-elems in registers
    float qreg[16];
    {
        const float4* qr = (const float4*)(q + ((long)b*T + qg)*Hh + sub*16);
        #pragma unroll
        for (int j = 0; j < 4; ++j) {
            const float4 t4 = qr[j];
            qreg[4*j+0]=t4.x; qreg[4*j+1]=t4.y; qreg[4*j+2]=t4.z; qreg[4*j+3]=t4.w;
        }
    }
    float o[16];
    #pragma unroll
    for (int i = 0; i < 16; ++i) o[i] = 0.f;
    float mrun = -INFINITY, lrun = 0.f;

    for (int kt = kt0; kt <= kt1; ++kt) {
        __syncthreads();                  // protect LDS from previous tile's readers
        {   // stage K and V tiles (64x64 fp32 each), coalesced float4
            const float4* kbase = (const float4*)(k + ((long)b*T + (long)kt*64)*Hh);
            const float4* vbase = (const float4*)(v + ((long)b*T + (long)kt*64)*Hh);
            for (int idx = t; idx < 1024; idx += 256) {
                const int rr = idx >> 4, cc = idx & 15;
                ((float4*)&kls[rr][0])[cc] = kbase[idx];
                ((float4*)&vls[rr][0])[cc] = vbase[idx];
            }
        }
        __syncthreads();

        for (int kk = 0; kk < 64; ++kk) {
            const long kg = (long)kt*64 + kk;
            if (kg > qg) break;           // causal (only triggers on diagonal tile)

            float sp = 0.f;
            const float4* kr = (const float4*)&kls[kk][sub*16];
            #pragma unroll
            for (int j = 0; j < 4; ++j) {
                const float4 kv = kr[j];
                sp += qreg[4*j+0]*kv.x + qreg[4*j+1]*kv.y
                    + qreg[4*j+2]*kv.z + qreg[4*j+3]*kv.w;
            }
            sp += __shfl_xor(sp, 1);
            sp += __shfl_xor(sp, 2);      // all 4 sub-lanes now hold full dot
            sp *= 0.0625f;                // C^-0.5 = 1/16

            if (sp > mrun) {              // rescale on new max
                const float corr = __expf(mrun - sp);   // exp(-inf)=0 on first hit
                lrun *= corr;
                #pragma unroll
                for (int i = 0; i < 16; ++i) o[i] *= corr;
                mrun = sp;
            }
            const float p = __expf(sp - mrun);
            lrun += p;
            const float4* vr = (const float4*)&vls[kk][sub*16];
            #pragma unroll
            for (int j = 0; j < 4; ++j) {
                const float4 vv = vr[j];
                o[4*j+0] += p*vv.x; o[4*j+1] += p*vv.y;
                o[4*j+2] += p*vv.z; o[4*j+3] += p*vv.w;
            }
        }
    }

    // write partials: o (unnormalized), m, l
    float* po = part_o + (long)bid*4096 + row*Hh + sub*16;
    #pragma unroll
    for (int j = 0; j < 4; ++j) {
        float4 ov = make_float4(o[4*j+0], o[4*j+1], o[4*j+2], o[4*j+3]);
        ((float4*)po)[j] = ov;
    }
    if (sub == 0) {
        part_ml[(long)bid*128 + row*2 + 0] = mrun;
        part_ml[(long)bid*128 + row*2 + 1] = lrun;
    }
}

// ---------------------------------------------------------------------------
// Merge <=4 segment partials per q-row, normalize, write output.
// grid = Bb*NQT = 256 blocks, 256 threads.
// ---------------------------------------------------------------------------
__global__ __launch_bounds__(256) void attn_merge(
    const float* __restrict__ part_o, const float* __restrict__ part_ml,
    float* __restrict__ out)
{
    const int bid = blockIdx.x;           // b*NQT + qt
    const int qt  = bid & (NQT-1);
    const int b   = bid >> 6;
    const int t   = threadIdx.x;
    const int row = t >> 2;
    const int sub = t & 3;
    const int nseg = qt / SEG_TILES + 1;  // valid segments for this q-tile
    const int base = bid * NSEG;          // partial-block index base

    float ms[NSEG], ls[NSEG];
    float mstar = -INFINITY;
    for (int s = 0; s < nseg; ++s) {
        ms[s] = part_ml[(long)(base+s)*128 + row*2 + 0];
        ls[s] = part_ml[(long)(base+s)*128 + row*2 + 1];
        mstar = fmaxf(mstar, ms[s]);
    }
    float acc[16];
    #pragma unroll
    for (int i = 0; i < 16; ++i) acc[i] = 0.f;
    float lsum = 0.f;
    for (int s = 0; s < nseg; ++s) {
        const float w = __expf(ms[s] - mstar);
        lsum += ls[s] * w;
        const float4* po = (const float4*)(part_o + (long)(base+s)*4096 + row*Hh + sub*16);
        #pragma unroll
        for (int j = 0; j < 4; ++j) {
            const float4 ov = po[j];
            acc[4*j+0] += w*ov.x; acc[4*j+1] += w*ov.y;
            acc[4*j+2] += w*ov.z; acc[4*j+3] += w*ov.w;
        }
    }
    const float inv = 1.f / lsum;
    float* op = out + ((long)b*T + (long)qt*64 + row)*Hh + sub*16;
    #pragma unroll
    for (int j = 0; j < 4; ++j) {
        float4 ov = make_float4(acc[4*j+0]*inv, acc[4*j+1]*inv,
                                acc[4*j+2]*inv, acc[4*j+3]*inv);
        ((float4*)op)[j] = ov;
    }
}

// ---------------------------------------------------------------------------
extern "C" void kernel_launch(void* const* d_in, const int* in_sizes, int n_in,
                              void* d_out, int out_size, void* d_ws, size_t ws_size,
                              hipStream_t stream)
{
    const float* x  = (const float*)d_in[0];
    const float* Wk = (const float*)d_in[1];
    const float* Wq = (const float*)d_in[2];
    const float* Wv = (const float*)d_in[3];

    float* ws      = (float*)d_ws;
    float* qb      = ws;                       // BT*Hh = 1M floats
    float* kb      = qb + (long)BT*Hh;
    float* vb      = kb + (long)BT*Hh;
    float* part_o  = vb + (long)BT*Hh;         // 1024 * 4096 floats
    float* part_ml = part_o + (long)Bb*NQT*NSEG*4096;  // 1024 * 128 floats

    proj_kernel<<<BT/64, 192, 0, stream>>>(x, Wk, Wq, Wv, qb, kb, vb);
    attn_partial<<<Bb*NQT*NSEG, 256, 0, stream>>>(qb, kb, vb, part_o, part_ml);
    attn_merge<<<Bb*NQT, 256, 0, stream>>>(part_o, part_ml, (float*)d_out);
}

// Round 2
// 191.695 us; speedup vs baseline: 2.9531x; 2.9531x over previous
//
#include <hip/hip_runtime.h>
#include <hip/hip_bf16.h>
#include <math.h>

// (B,T,C,H) = (4,4096,256,64)
#define Bb   4
#define T    4096
#define Cc   256
#define Hh   64
#define BT   (Bb*T)
#define QB   32           // q rows per block (2 waves x 16 rows)
#define NQT  (T/QB)       // 128 q-tiles per batch

using f32x4  = __attribute__((ext_vector_type(4))) float;
using short8 = __attribute__((ext_vector_type(8))) short;

// byte offset into a [rows][64 bf16] LDS tile, XOR-swizzled (G4: breaks the
// 128B row-stride 16-way bank conflict for ds_read_b128 column slices)
__device__ __forceinline__ int swzb(int row, int colbyte) {
    return ((row << 7) + colbyte) ^ ((row & 7) << 4);
}
__device__ __forceinline__ ushort f2bf(float f) {   // round-to-nearest-ish
    unsigned u = __builtin_bit_cast(unsigned, f);
    return (ushort)((u + 0x8000u) >> 16);
}

// ---------------------------------------------------------------------------
// Projection: q/k/v[row][h] = sum_c x[row][c] * W[c][h], bf16 out.
// Scale C^-0.5 = 1/16 folded into q. grid = 256 blocks x 192 threads.
// ---------------------------------------------------------------------------
__global__ __launch_bounds__(192) void proj_kernel(
    const float* __restrict__ x,
    const float* __restrict__ Wk, const float* __restrict__ Wq,
    const float* __restrict__ Wv,
    ushort* __restrict__ qo, ushort* __restrict__ ko, ushort* __restrict__ vo)
{
    __shared__ float xs[Cc][64];          // transposed x tile
    const int t = threadIdx.x;
    const long rowbase = (long)blockIdx.x * 64;

    for (int idx = t; idx < 64 * (Cc/4); idx += 192) {
        const int r  = idx / (Cc/4);
        const int c4 = idx % (Cc/4);
        const float4 xv = ((const float4*)x)[rowbase*(Cc/4) + r*(Cc/4) + c4];
        xs[c4*4+0][r] = xv.x; xs[c4*4+1][r] = xv.y;
        xs[c4*4+2][r] = xv.z; xs[c4*4+3][r] = xv.w;
    }
    __syncthreads();

    const int h = t & 63;
    const int m = t >> 6;                 // 0=q 1=k 2=v
    const float* W    = (m == 0) ? Wq : (m == 1) ? Wk : Wv;
    ushort*      outp = (m == 0) ? qo : (m == 1) ? ko : vo;
    const float scale = (m == 0) ? 0.0625f : 1.0f;

    for (int r0 = 0; r0 < 64; r0 += 16) {
        float acc[16];
        #pragma unroll
        for (int i = 0; i < 16; ++i) acc[i] = 0.f;
        #pragma unroll 4
        for (int c = 0; c < Cc; ++c) {
            const float w = W[c*Hh + h];
            const float4* xr = (const float4*)&xs[c][r0];
            #pragma unroll
            for (int j = 0; j < 4; ++j) {
                const float4 xv = xr[j];
                acc[j*4+0] += xv.x * w; acc[j*4+1] += xv.y * w;
                acc[j*4+2] += xv.z * w; acc[j*4+3] += xv.w * w;
            }
        }
        #pragma unroll
        for (int i = 0; i < 16; ++i)
            outp[(rowbase + r0 + i)*Hh + h] = f2bf(acc[i] * scale);
    }
}

// ---------------------------------------------------------------------------
// Fused causal flash attention, bf16 MFMA (16x16x32).
// grid = Bb*NQT = 512 blocks, 128 threads (2 waves, 16 q-rows each).
// ---------------------------------------------------------------------------
__global__ __launch_bounds__(128) void attn_mfma(
    const ushort* __restrict__ q, const ushort* __restrict__ k,
    const ushort* __restrict__ v, float* __restrict__ out)
{
    __shared__ ushort kls[64*64];        // K tile  [key][h], swizzled
    __shared__ ushort vtls[64*64];       // V^T tile [h][key], swizzled
    __shared__ ushort pls[2][16*64];     // per-wave P tile [m][key], swizzled

    const int bid = blockIdx.x;
    const int b   = bid & 3;
    const int qt  = (NQT - 1) - (bid >> 2);   // big q-tiles dispatch first
    const int t    = threadIdx.x;
    const int w    = t >> 6;
    const int lane = t & 63;
    const int g    = lane >> 4;
    const int ln   = lane & 15;
    const int ktmax = qt >> 1;                 // last 64-key tile index
    const int qbase = (qt & 1) * 32 + w * 16;  // q offset inside diagonal tile

    // Q fragments (A-layout: row = lane&15, k = g*8.., 2 K-steps of 32)
    short8 qf[2];
    {
        const ushort* qp = q + ((long)(b*T + qt*QB + w*16 + ln)) * Hh;
        qf[0] = *(const short8*)(qp + g*8);
        qf[1] = *(const short8*)(qp + 32 + g*8);
    }

    f32x4 oacc[4];
    #pragma unroll
    for (int i = 0; i < 4; ++i) oacc[i] = (f32x4){0.f, 0.f, 0.f, 0.f};
    float mrun[4], lrun[4];
    #pragma unroll
    for (int r = 0; r < 4; ++r) { mrun[r] = -INFINITY; lrun[r] = 0.f; }

    for (int kt = 0; kt <= ktmax; ++kt) {
        __syncthreads();                  // previous tile's LDS readers done
        {   // stage K (swizzled) and V^T (transpose-scatter, swizzled)
            const ushort* kb = k + ((long)b*T + (long)kt*64) * Hh;
            const ushort* vb = v + ((long)b*T + (long)kt*64) * Hh;
            #pragma unroll
            for (int i = 0; i < 4; ++i) {
                const int c   = t + i*128;       // 512 16B chunks
                const int key = c >> 3;
                const int h0  = (c & 7) * 8;
                short8 k8 = *(const short8*)(kb + key*Hh + h0);
                *(short8*)((char*)kls + swzb(key, h0*2)) = k8;
                short8 v8 = *(const short8*)(vb + key*Hh + h0);
                #pragma unroll
                for (int j = 0; j < 8; ++j)
                    *(ushort*)((char*)vtls + swzb(h0 + j, key*2)) = (ushort)v8[j];
            }
        }
        __syncthreads();

        // S = Q K^T : D[q][key], 4 key-16-tiles x 2 K-steps
        f32x4 s[4];
        #pragma unroll
        for (int i = 0; i < 4; ++i) s[i] = (f32x4){0.f, 0.f, 0.f, 0.f};
        #pragma unroll
        for (int ks = 0; ks < 2; ++ks) {
            #pragma unroll
            for (int nt = 0; nt < 4; ++nt) {
                const short8 bk = *(const short8*)((const char*)kls +
                                     swzb(nt*16 + ln, ks*64 + g*16));
                s[nt] = __builtin_amdgcn_mfma_f32_16x16x32_bf16(qf[ks], bk, s[nt], 0, 0, 0);
            }
        }

        if (kt == ktmax) {                // causal mask on the diagonal tile
            #pragma unroll
            for (int nt = 0; nt < 4; ++nt)
                #pragma unroll
                for (int r = 0; r < 4; ++r)
                    if (nt*16 + ln > qbase + g*4 + r) s[nt][r] = -INFINITY;
        }

        // online softmax (wave-parallel, 16-lane butterflies)
        float mt[4];
        #pragma unroll
        for (int r = 0; r < 4; ++r)
            mt[r] = fmaxf(fmaxf(s[0][r], s[1][r]), fmaxf(s[2][r], s[3][r]));
        #pragma unroll
        for (int d = 1; d < 16; d <<= 1)
            #pragma unroll
            for (int r = 0; r < 4; ++r) {
                const float o = __shfl_xor(mt[r], d);
                mt[r] = fmaxf(mt[r], o);
            }
        float corr[4], psum[4];
        #pragma unroll
        for (int r = 0; r < 4; ++r) {
            const float mn = fmaxf(mrun[r], mt[r]);
            corr[r] = __expf(mrun[r] - mn);
            mrun[r] = mn;
            psum[r] = 0.f;
        }
        #pragma unroll
        for (int nt = 0; nt < 4; ++nt)
            #pragma unroll
            for (int r = 0; r < 4; ++r) {
                const float p = __expf(s[nt][r] - mrun[r]);
                psum[r] += p;
                *(ushort*)((char*)pls[w] + swzb(g*4 + r, (nt*16 + ln)*2)) = f2bf(p);
            }
        #pragma unroll
        for (int d = 1; d < 16; d <<= 1)
            #pragma unroll
            for (int r = 0; r < 4; ++r) {
                const float o = __shfl_xor(psum[r], d);
                psum[r] += o;
            }
        #pragma unroll
        for (int r = 0; r < 4; ++r)
            lrun[r] = lrun[r] * corr[r] + psum[r];
        #pragma unroll
        for (int nt = 0; nt < 4; ++nt)
            #pragma unroll
            for (int r = 0; r < 4; ++r)
                oacc[nt][r] *= corr[r];

        // O += P V : A = P from LDS, B = V^T tile
        #pragma unroll
        for (int ks = 0; ks < 2; ++ks) {
            const short8 pa = *(const short8*)((const char*)pls[w] +
                                 swzb(ln, ks*64 + g*16));
            #pragma unroll
            for (int nt = 0; nt < 4; ++nt) {
                const short8 bv = *(const short8*)((const char*)vtls +
                                     swzb(nt*16 + ln, ks*64 + g*16));
                oacc[nt] = __builtin_amdgcn_mfma_f32_16x16x32_bf16(pa, bv, oacc[nt], 0, 0, 0);
            }
        }
    }

    // epilogue: normalize, write fp32
    float inv[4];
    #pragma unroll
    for (int r = 0; r < 4; ++r) inv[r] = 1.f / lrun[r];
    #pragma unroll
    for (int nt = 0; nt < 4; ++nt)
        #pragma unroll
        for (int r = 0; r < 4; ++r)
            out[((long)(b*T + qt*QB + w*16 + g*4 + r))*Hh + nt*16 + ln] =
                oacc[nt][r] * inv[r];
}

// ---------------------------------------------------------------------------
extern "C" void kernel_launch(void* const* d_in, const int* in_sizes, int n_in,
                              void* d_out, int out_size, void* d_ws, size_t ws_size,
                              hipStream_t stream)
{
    const float* x  = (const float*)d_in[0];
    const float* Wk = (const float*)d_in[1];
    const float* Wq = (const float*)d_in[2];
    const float* Wv = (const float*)d_in[3];

    ushort* qb = (ushort*)d_ws;               // BT*Hh bf16 each
    ushort* kb = qb + (long)BT*Hh;
    ushort* vb = kb + (long)BT*Hh;

    proj_kernel<<<BT/64, 192, 0, stream>>>(x, Wk, Wq, Wv, qb, kb, vb);
    attn_mfma<<<Bb*NQT, 128, 0, stream>>>(qb, kb, vb, (float*)d_out);
}

// Round 3
// 74.039 us; speedup vs baseline: 7.6459x; 2.5891x over previous
//
#include <hip/hip_runtime.h>
#include <hip/hip_bf16.h>
#include <math.h>

// (B,T,C,H) = (4,4096,256,64)
#define Bb   4
#define T    4096
#define Cc   256
#define Hh   64
#define BT   (Bb*T)

using f32x4  = __attribute__((ext_vector_type(4))) float;
using short8 = __attribute__((ext_vector_type(8))) short;

__device__ __forceinline__ ushort f2bf(float f) {
    unsigned u = __builtin_bit_cast(unsigned, f);
    return (ushort)((u + 0x8000u) >> 16);
}
// swizzled byte offset, [rows][128B] tile (64 bf16 cols)
__device__ __forceinline__ int swzb(int row, int cb) { return (row<<7) + (cb ^ ((row&7)<<4)); }
// swizzled byte offset, [rows][512B] tile (256 bf16 cols)
__device__ __forceinline__ int swzx(int row, int cb) { return (row<<9) + (cb ^ ((row&7)<<4)); }

#define GLOAD16(g, l) __builtin_amdgcn_global_load_lds( \
    (const __attribute__((address_space(1))) unsigned*)(g), \
    (__attribute__((address_space(3))) unsigned*)(l), 16, 0, 0)

// ---------------------------------------------------------------------------
// Pack Wq|Wk|Wv -> Wt bf16 [192][256], PRE-SWIZZLED rows (512B), 1/16 in Wq.
// ---------------------------------------------------------------------------
__global__ __launch_bounds__(256) void wtrans(
    const float* __restrict__ Wq, const float* __restrict__ Wk,
    const float* __restrict__ Wv, ushort* __restrict__ WtG)
{
    __shared__ float wl[256][65];
    const int t = threadIdx.x;
    const int m = blockIdx.x;                  // 0=q 1=k 2=v
    const float* W = (m==0) ? Wq : (m==1) ? Wk : Wv;
    const float scale = (m==0) ? 0.0625f : 1.0f;
    for (int idx = t; idx < 4096; idx += 256) {          // 4096 float4 = 256x64
        const float4 v4 = ((const float4*)W)[idx];
        const int c = idx >> 4;
        const int h = (idx & 15) * 4;
        wl[c][h+0]=v4.x*scale; wl[c][h+1]=v4.y*scale;
        wl[c][h+2]=v4.z*scale; wl[c][h+3]=v4.w*scale;
    }
    __syncthreads();
    const int h  = t & 63;
    const int n  = m*64 + h;
    const int c0 = (t >> 6) * 64;
    for (int c = c0; c < c0 + 64; c += 4) {
        ushort4 o;
        o.x=f2bf(wl[c+0][h]); o.y=f2bf(wl[c+1][h]);
        o.z=f2bf(wl[c+2][h]); o.w=f2bf(wl[c+3][h]);
        *(ushort4*)((char*)WtG + n*512 + ((c*2) ^ ((n&7)<<4))) = o;   // pre-swizzled
    }
}

// ---------------------------------------------------------------------------
// MFMA projection: q,k row-major bf16 (swapped-operand) + vT [b][h][T] bf16.
// grid 256 x 256 thr (4 waves, 16 rows each).
// ---------------------------------------------------------------------------
__global__ __launch_bounds__(256) void proj_mfma(
    const float* __restrict__ x, const ushort* __restrict__ WtG,
    ushort* __restrict__ qo, ushort* __restrict__ ko, ushort* __restrict__ vtG)
{
    __shared__ ushort xls[64*256];     // 32KB, swizzled 512B rows
    __shared__ ushort wls[192*256];    // 96KB, content pre-swizzled
    const int t = threadIdx.x, w = t>>6, lane = t&63, g = lane>>4, ln = lane&15;
    const int blk = blockIdx.x;
    const long rowbase = (long)blk * 64;
    const int b    = blk >> 6;                 // 64 blocks per batch
    const int trow = (blk & 63) * 64;

    {   // Wt: 96KB linear global->LDS copy (content already swizzled)
        const char* src = (const char*)WtG + (long)lane*16;
        for (int c = w; c < 96; c += 4)
            GLOAD16(src + c*1024, (char*)wls + c*1024);
    }
    // x tile: 64 rows x 256 c fp32 -> bf16 swizzled
    for (int j = 0; j < 16; ++j) {
        const int idx = t + j*256;
        const int row = idx >> 6;
        const int c4  = (idx & 63) * 4;
        const float4 xv = ((const float4*)x)[(rowbase + row)*64 + (c4>>2)];
        ushort4 o; o.x=f2bf(xv.x); o.y=f2bf(xv.y); o.z=f2bf(xv.z); o.w=f2bf(xv.w);
        *(ushort4*)((char*)xls + swzx(row, c4*2)) = o;
    }
    __syncthreads();

    short8 xf[8];
    #pragma unroll
    for (int ks = 0; ks < 8; ++ks)
        xf[ks] = *(const short8*)((const char*)xls + swzx(w*16+ln, ks*64 + g*16));

    #pragma unroll
    for (int nt = 0; nt < 12; ++nt) {
        f32x4 acc = (f32x4){0.f,0.f,0.f,0.f};
        #pragma unroll
        for (int ks = 0; ks < 8; ++ks) {
            const short8 wf = *(const short8*)((const char*)wls + swzx(nt*16+ln, ks*64 + g*16));
            acc = (nt < 8) ? __builtin_amdgcn_mfma_f32_16x16x32_bf16(wf, xf[ks], acc, 0,0,0)
                           : __builtin_amdgcn_mfma_f32_16x16x32_bf16(xf[ks], wf, acc, 0,0,0);
        }
        ushort4 o; o.x=f2bf(acc[0]); o.y=f2bf(acc[1]); o.z=f2bf(acc[2]); o.w=f2bf(acc[3]);
        if (nt < 4) {        // q: lane row = rowbase+w*16+ln, cols nt*16+g*4..+3
            *(ushort4*)(qo + (rowbase + w*16 + ln)*64 + nt*16 + g*4) = o;
        } else if (nt < 8) { // k
            *(ushort4*)(ko + (rowbase + w*16 + ln)*64 + (nt-4)*16 + g*4) = o;
        } else {             // v (unswapped): lane h = (nt-8)*16+ln, rows = 4 consecutive t
            *(ushort4*)(vtG + ((long)b*64 + (nt-8)*16 + ln)*T + trow + w*16 + g*4) = o;
        }
    }
}

// ---------------------------------------------------------------------------
// Flash attention partial: QB=64, parity k-split, double-buffered gload staging.
// grid = 512 (qt big-first x b x s), 256 thr (4 waves x 16 q-rows).
// ---------------------------------------------------------------------------
__global__ __launch_bounds__(256) void attn_mfma(
    const ushort* __restrict__ q, const ushort* __restrict__ k,
    const ushort* __restrict__ vt,
    float* __restrict__ part_o, float* __restrict__ part_ml)
{
    __shared__ ushort kls[2][64*64];     // K  [key][h], swizzled, dbuf
    __shared__ ushort vtls[2][64*64];    // V^T [h][key], swizzled, dbuf
    __shared__ ushort pls[4][16*64];     // per-wave P [m][key], swizzled

    const int bid = blockIdx.x;
    const int qt  = 63 - (bid >> 3);
    const int b   = (bid >> 1) & 3;
    const int s   = bid & 1;
    const int ntile = (qt >= s) ? ((qt - s) >> 1) + 1 : 0;
    if (ntile == 0) return;              // only (qt=0, s=1)

    const int t = threadIdx.x, w = t>>6, lane = t&63, g = lane>>4, ln = lane&15;
    const int lrow = lane >> 3;                 // staging: row-in-chunk
    const int lc16 = ((lane & 7) ^ lrow) * 16;  // pre-swizzled 16B slot
    const char* kbase = (const char*)k  + ((long)b*T)*128;
    const char* vbase = (const char*)vt + ((long)b*64)*(long)T*2;

    #define STAGE(bufi, ktile) do { \
        _Pragma("unroll") for (int j = 0; j < 2; ++j) { const int ci = w*2 + j; \
            GLOAD16(kbase + (long)(ktile)*8192 + ci*1024 + lrow*128 + lc16, \
                    (char*)kls[bufi] + ci*1024); \
            GLOAD16(vbase + ((long)(8*ci + lrow))*8192 + (long)(ktile)*128 + lc16, \
                    (char*)vtls[bufi] + ci*1024); \
        } } while(0)

    // Q fragments
    short8 qf[2];
    {
        const ushort* qp = q + ((long)(b*T + qt*64 + w*16 + ln))*64;
        qf[0] = *(const short8*)(qp + g*8);
        qf[1] = *(const short8*)(qp + 32 + g*8);
    }
    f32x4 oacc[4];
    #pragma unroll
    for (int i = 0; i < 4; ++i) oacc[i] = (f32x4){0.f,0.f,0.f,0.f};
    float mrun[4], lrun[4];
    #pragma unroll
    for (int r = 0; r < 4; ++r) { mrun[r] = -INFINITY; lrun[r] = 0.f; }

    STAGE(0, s);
    for (int it = 0; it < ntile; ++it) {
        const int kt  = s + 2*it;
        const int cur = it & 1;
        __syncthreads();                       // drains cur stage; ends prev compute
        if (it + 1 < ntile) STAGE(cur^1, kt + 2);

        // S = Q K^T
        f32x4 sf[4];
        #pragma unroll
        for (int i = 0; i < 4; ++i) sf[i] = (f32x4){0.f,0.f,0.f,0.f};
        #pragma unroll
        for (int ks = 0; ks < 2; ++ks)
            #pragma unroll
            for (int nt = 0; nt < 4; ++nt) {
                const short8 bk = *(const short8*)((const char*)kls[cur] +
                                     swzb(nt*16 + ln, ks*64 + g*16));
                sf[nt] = __builtin_amdgcn_mfma_f32_16x16x32_bf16(qf[ks], bk, sf[nt], 0,0,0);
            }
        if (kt == qt) {                        // causal mask on diagonal
            #pragma unroll
            for (int nt = 0; nt < 4; ++nt)
                #pragma unroll
                for (int r = 0; r < 4; ++r)
                    if (nt*16 + ln > w*16 + g*4 + r) sf[nt][r] = -INFINITY;
        }
        // online softmax (16-lane butterflies)
        float mt[4];
        #pragma unroll
        for (int r = 0; r < 4; ++r)
            mt[r] = fmaxf(fmaxf(sf[0][r], sf[1][r]), fmaxf(sf[2][r], sf[3][r]));
        #pragma unroll
        for (int d = 1; d < 16; d <<= 1)
            #pragma unroll
            for (int r = 0; r < 4; ++r)
                mt[r] = fmaxf(mt[r], __shfl_xor(mt[r], d));
        float corr[4], psum[4];
        #pragma unroll
        for (int r = 0; r < 4; ++r) {
            const float mn = fmaxf(mrun[r], mt[r]);
            corr[r] = __expf(mrun[r] - mn);
            mrun[r] = mn; psum[r] = 0.f;
        }
        #pragma unroll
        for (int nt = 0; nt < 4; ++nt)
            #pragma unroll
            for (int r = 0; r < 4; ++r) {
                const float p = __expf(sf[nt][r] - mrun[r]);
                psum[r] += p;
                *(ushort*)((char*)pls[w] + swzb(g*4 + r, (nt*16 + ln)*2)) = f2bf(p);
            }
        #pragma unroll
        for (int d = 1; d < 16; d <<= 1)
            #pragma unroll
            for (int r = 0; r < 4; ++r)
                psum[r] += __shfl_xor(psum[r], d);
        #pragma unroll
        for (int r = 0; r < 4; ++r) lrun[r] = lrun[r]*corr[r] + psum[r];
        #pragma unroll
        for (int nt = 0; nt < 4; ++nt)
            #pragma unroll
            for (int r = 0; r < 4; ++r) oacc[nt][r] *= corr[r];

        // O += P V
        #pragma unroll
        for (int ks = 0; ks < 2; ++ks) {
            const short8 pa = *(const short8*)((const char*)pls[w] +
                                 swzb(ln, ks*64 + g*16));
            #pragma unroll
            for (int nt = 0; nt < 4; ++nt) {
                const short8 bv = *(const short8*)((const char*)vtls[cur] +
                                     swzb(nt*16 + ln, ks*64 + g*16));
                oacc[nt] = __builtin_amdgcn_mfma_f32_16x16x32_bf16(pa, bv, oacc[nt], 0,0,0);
            }
        }
    }
    #undef STAGE

    const long pbase = (long)bid * 4096;
    #pragma unroll
    for (int nt = 0; nt < 4; ++nt)
        #pragma unroll
        for (int r = 0; r < 4; ++r)
            part_o[pbase + (w*16 + g*4 + r)*64 + nt*16 + ln] = oacc[nt][r];
    if (ln == 0)
        #pragma unroll
        for (int r = 0; r < 4; ++r) {
            part_ml[(long)bid*128 + (w*16 + g*4 + r)*2 + 0] = mrun[r];
            part_ml[(long)bid*128 + (w*16 + g*4 + r)*2 + 1] = lrun[r];
        }
}

// ---------------------------------------------------------------------------
// Merge 2 parity partials per q-row, normalize, write fp32 output.
// ---------------------------------------------------------------------------
__global__ __launch_bounds__(256) void attn_merge(
    const float* __restrict__ part_o, const float* __restrict__ part_ml,
    float* __restrict__ out)
{
    const int bid = blockIdx.x;                // b*64 + qt
    const int b = bid >> 6, qt = bid & 63;
    const int t = threadIdx.x, row = t >> 2, sub = t & 3;
    const int base = ((63 - qt) << 3) | (b << 1);

    const float m0 = part_ml[(long)base*128 + row*2 + 0];
    const float l0 = part_ml[(long)base*128 + row*2 + 1];
    float m1 = -INFINITY, l1 = 0.f;
    if (qt > 0) {
        m1 = part_ml[(long)(base+1)*128 + row*2 + 0];
        l1 = part_ml[(long)(base+1)*128 + row*2 + 1];
    }
    const float ms = fmaxf(m0, m1);
    const float w0 = __expf(m0 - ms);
    const float w1 = (qt > 0) ? __expf(m1 - ms) : 0.f;
    const float inv = 1.f / (l0*w0 + l1*w1);

    const float4* p0 = (const float4*)(part_o + (long)base*4096 + row*64 + sub*16);
    const float4* p1 = (const float4*)(part_o + (long)(base+1)*4096 + row*64 + sub*16);
    float* op = out + ((long)b*T + qt*64 + row)*64 + sub*16;
    #pragma unroll
    for (int j = 0; j < 4; ++j) {
        const float4 a = p0[j];
        float4 r = make_float4(a.x*w0, a.y*w0, a.z*w0, a.w*w0);
        if (qt > 0) {
            const float4 c = p1[j];
            r.x += c.x*w1; r.y += c.y*w1; r.z += c.z*w1; r.w += c.w*w1;
        }
        ((float4*)op)[j] = make_float4(r.x*inv, r.y*inv, r.z*inv, r.w*inv);
    }
}

// ---------------------------------------------------------------------------
extern "C" void kernel_launch(void* const* d_in, const int* in_sizes, int n_in,
                              void* d_out, int out_size, void* d_ws, size_t ws_size,
                              hipStream_t stream)
{
    const float* x  = (const float*)d_in[0];
    const float* Wk = (const float*)d_in[1];
    const float* Wq = (const float*)d_in[2];
    const float* Wv = (const float*)d_in[3];

    char* w8 = (char*)d_ws;
    ushort* qb      = (ushort*)(w8);                    // 2 MB
    ushort* kb      = (ushort*)(w8 + (2l<<20));         // 2 MB
    ushort* vt      = (ushort*)(w8 + (4l<<20));         // 2 MB
    ushort* Wt      = (ushort*)(w8 + (6l<<20));         // 96 KB
    float*  part_o  = (float*) (w8 + (7l<<20));         // 8 MB
    float*  part_ml = (float*) (w8 + (15l<<20));        // 256 KB

    wtrans   <<<3,   256, 0, stream>>>(Wq, Wk, Wv, Wt);
    proj_mfma<<<256, 256, 0, stream>>>(x, Wt, qb, kb, vt);
    attn_mfma<<<512, 256, 0, stream>>>(qb, kb, vt, part_o, part_ml);
    attn_merge<<<256,256, 0, stream>>>(part_o, part_ml, (float*)d_out);
}

// Round 4
// 55.646 us; speedup vs baseline: 10.1731x; 1.3305x over previous
//
#include <hip/hip_runtime.h>
#include <hip/hip_bf16.h>
#include <math.h>

// (B,T,C,H) = (4,4096,256,64)
#define Bb   4
#define T    4096
#define Cc   256
#define Hh   64
#define BT   (Bb*T)
#define CHUNK 8              // k-tiles (of 64 keys) per attention block
#define CPB  288             // chunks per batch = sum_qt ceil((qt+1)/8)

using f32x4  = __attribute__((ext_vector_type(4))) float;
using short8 = __attribute__((ext_vector_type(8))) short;

__device__ __forceinline__ ushort f2bf(float f) {
    unsigned u = __builtin_bit_cast(unsigned, f);
    return (ushort)((u + 0x8000u) >> 16);
}
__device__ __forceinline__ float bf2f(ushort u) {
    return __builtin_bit_cast(float, (unsigned)u << 16);
}
// swizzled byte offset, [rows][128B] tile (64 bf16 cols)
__device__ __forceinline__ int swzb(int row, int cb) { return (row<<7) + (cb ^ ((row&7)<<4)); }
// swizzled byte offset, [rows][512B] tile (256 bf16 cols)
__device__ __forceinline__ int swzx(int row, int cb) { return (row<<9) + (cb ^ ((row&7)<<4)); }
// partial-chunk prefix: f(qt) = #chunks for q-tiles < qt
__device__ __forceinline__ int chunk_prefix(int qt) {
    const int a = qt >> 3, r = qt & 7;
    return 4*a*(a+1) + r*(a+1);
}

#define GLOAD16(g, l) __builtin_amdgcn_global_load_lds( \
    (const __attribute__((address_space(1))) unsigned*)(g), \
    (__attribute__((address_space(3))) unsigned*)(l), 16, 0, 0)

// ---------------------------------------------------------------------------
// Pack Wq|Wk|Wv -> Wt bf16 [192][256], PRE-SWIZZLED rows (512B), 1/16 in Wq.
// ---------------------------------------------------------------------------
__global__ __launch_bounds__(256) void wtrans(
    const float* __restrict__ Wq, const float* __restrict__ Wk,
    const float* __restrict__ Wv, ushort* __restrict__ WtG)
{
    __shared__ float wl[256][65];
    const int t = threadIdx.x;
    const int m = blockIdx.x;                  // 0=q 1=k 2=v
    const float* W = (m==0) ? Wq : (m==1) ? Wk : Wv;
    const float scale = (m==0) ? 0.0625f : 1.0f;
    for (int idx = t; idx < 4096; idx += 256) {
        const float4 v4 = ((const float4*)W)[idx];
        const int c = idx >> 4;
        const int h = (idx & 15) * 4;
        wl[c][h+0]=v4.x*scale; wl[c][h+1]=v4.y*scale;
        wl[c][h+2]=v4.z*scale; wl[c][h+3]=v4.w*scale;
    }
    __syncthreads();
    const int h  = t & 63;
    const int n  = m*64 + h;
    const int c0 = (t >> 6) * 64;
    for (int c = c0; c < c0 + 64; c += 4) {
        ushort4 o;
        o.x=f2bf(wl[c+0][h]); o.y=f2bf(wl[c+1][h]);
        o.z=f2bf(wl[c+2][h]); o.w=f2bf(wl[c+3][h]);
        *(ushort4*)((char*)WtG + n*512 + ((c*2) ^ ((n&7)<<4))) = o;
    }
}

// ---------------------------------------------------------------------------
// MFMA projection: q,k row-major bf16 (swapped-operand) + vT [b][h][T] bf16.
// ---------------------------------------------------------------------------
__global__ __launch_bounds__(256) void proj_mfma(
    const float* __restrict__ x, const ushort* __restrict__ WtG,
    ushort* __restrict__ qo, ushort* __restrict__ ko, ushort* __restrict__ vtG)
{
    __shared__ ushort xls[64*256];     // 32KB, swizzled 512B rows
    __shared__ ushort wls[192*256];    // 96KB, content pre-swizzled
    const int t = threadIdx.x, w = t>>6, lane = t&63, g = lane>>4, ln = lane&15;
    const int blk = blockIdx.x;
    const long rowbase = (long)blk * 64;
    const int b    = blk >> 6;
    const int trow = (blk & 63) * 64;

    {   // Wt: 96KB linear global->LDS copy (content already swizzled)
        const char* src = (const char*)WtG + (long)lane*16;
        for (int c = w; c < 96; c += 4)
            GLOAD16(src + c*1024, (char*)wls + c*1024);
    }
    for (int j = 0; j < 16; ++j) {
        const int idx = t + j*256;
        const int row = idx >> 6;
        const int c4  = (idx & 63) * 4;
        const float4 xv = ((const float4*)x)[(rowbase + row)*64 + (c4>>2)];
        ushort4 o; o.x=f2bf(xv.x); o.y=f2bf(xv.y); o.z=f2bf(xv.z); o.w=f2bf(xv.w);
        *(ushort4*)((char*)xls + swzx(row, c4*2)) = o;
    }
    __syncthreads();

    short8 xf[8];
    #pragma unroll
    for (int ks = 0; ks < 8; ++ks)
        xf[ks] = *(const short8*)((const char*)xls + swzx(w*16+ln, ks*64 + g*16));

    #pragma unroll
    for (int nt = 0; nt < 12; ++nt) {
        f32x4 acc = (f32x4){0.f,0.f,0.f,0.f};
        #pragma unroll
        for (int ks = 0; ks < 8; ++ks) {
            const short8 wf = *(const short8*)((const char*)wls + swzx(nt*16+ln, ks*64 + g*16));
            acc = (nt < 8) ? __builtin_amdgcn_mfma_f32_16x16x32_bf16(wf, xf[ks], acc, 0,0,0)
                           : __builtin_amdgcn_mfma_f32_16x16x32_bf16(xf[ks], wf, acc, 0,0,0);
        }
        ushort4 o; o.x=f2bf(acc[0]); o.y=f2bf(acc[1]); o.z=f2bf(acc[2]); o.w=f2bf(acc[3]);
        if (nt < 4) {
            *(ushort4*)(qo + (rowbase + w*16 + ln)*64 + nt*16 + g*4) = o;
        } else if (nt < 8) {
            *(ushort4*)(ko + (rowbase + w*16 + ln)*64 + (nt-4)*16 + g*4) = o;
        } else {
            *(ushort4*)(vtG + ((long)b*64 + (nt-8)*16 + ln)*T + trow + w*16 + g*4) = o;
        }
    }
}

// ---------------------------------------------------------------------------
// Flash attention partial, balanced chunks: each block = (b, qt, c) covering
// k-tiles [8c, min(qt,8c+7)]. grid = 4*288 = 1152 blocks, 256 thr.
// Defer-max (THR=8) + out-of-loop l reduction.
// ---------------------------------------------------------------------------
__global__ __launch_bounds__(256) void attn_mfma(
    const ushort* __restrict__ q, const ushort* __restrict__ k,
    const ushort* __restrict__ vt,
    ushort* __restrict__ part_o, float* __restrict__ part_ml)
{
    __shared__ ushort kls[2][64*64];     // K  [key][h], swizzled, dbuf
    __shared__ ushort vtls[2][64*64];    // V^T [h][key], swizzled, dbuf
    __shared__ ushort pls[4][16*64];     // per-wave P [m][key], swizzled

    const int bid   = blockIdx.x;
    const int b     = bid & 3;
    const int w2    = (CPB - 1) - (bid >> 2);      // big q-tiles first
    int qt = 0, c = 0;
    {
        int acc = 0;
        for (int qq = 0; qq < 64; ++qq) {
            const int n = (qq >> 3) + 1;
            if (w2 < acc + n) { qt = qq; c = w2 - acc; break; }
            acc += n;
        }
    }
    const int kt0   = c * CHUNK;
    const int ntile = min(qt, kt0 + CHUNK - 1) - kt0 + 1;
    const int pid   = b*CPB + chunk_prefix(qt) + c;

    const int t = threadIdx.x, w = t>>6, lane = t&63, g = lane>>4, ln = lane&15;
    const int lrow = lane >> 3;
    const int lc16 = ((lane & 7) ^ lrow) * 16;
    const char* kbase = (const char*)k  + ((long)b*T)*128;
    const char* vbase = (const char*)vt + ((long)b*64)*(long)T*2;

    #define STAGE(bufi, ktile) do { \
        _Pragma("unroll") for (int j = 0; j < 2; ++j) { const int ci = w*2 + j; \
            GLOAD16(kbase + (long)(ktile)*8192 + ci*1024 + lrow*128 + lc16, \
                    (char*)kls[bufi] + ci*1024); \
            GLOAD16(vbase + ((long)(8*ci + lrow))*8192 + (long)(ktile)*128 + lc16, \
                    (char*)vtls[bufi] + ci*1024); \
        } } while(0)

    short8 qf[2];
    {
        const ushort* qp = q + ((long)(b*T + qt*64 + w*16 + ln))*64;
        qf[0] = *(const short8*)(qp + g*8);
        qf[1] = *(const short8*)(qp + 32 + g*8);
    }
    f32x4 oacc[4];
    #pragma unroll
    for (int i = 0; i < 4; ++i) oacc[i] = (f32x4){0.f,0.f,0.f,0.f};
    float mrun[4], lpart[4];
    #pragma unroll
    for (int r = 0; r < 4; ++r) { mrun[r] = -INFINITY; lpart[r] = 0.f; }

    STAGE(0, kt0);
    for (int it = 0; it < ntile; ++it) {
        const int kt  = kt0 + it;
        const int cur = it & 1;
        __syncthreads();
        if (it + 1 < ntile) STAGE(cur^1, kt + 1);

        // S = Q K^T
        f32x4 sf[4];
        #pragma unroll
        for (int i = 0; i < 4; ++i) sf[i] = (f32x4){0.f,0.f,0.f,0.f};
        __builtin_amdgcn_s_setprio(1);
        #pragma unroll
        for (int ks = 0; ks < 2; ++ks)
            #pragma unroll
            for (int nt = 0; nt < 4; ++nt) {
                const short8 bk = *(const short8*)((const char*)kls[cur] +
                                     swzb(nt*16 + ln, ks*64 + g*16));
                sf[nt] = __builtin_amdgcn_mfma_f32_16x16x32_bf16(qf[ks], bk, sf[nt], 0,0,0);
            }
        __builtin_amdgcn_s_setprio(0);
        if (kt == qt) {                        // causal mask on diagonal
            #pragma unroll
            for (int nt = 0; nt < 4; ++nt)
                #pragma unroll
                for (int r = 0; r < 4; ++r)
                    if (nt*16 + ln > w*16 + g*4 + r) sf[nt][r] = -INFINITY;
        }

        // defer-max vote: any value above mrun + 8 ?
        bool ok = true;
        #pragma unroll
        for (int nt = 0; nt < 4; ++nt)
            #pragma unroll
            for (int r = 0; r < 4; ++r)
                ok &= (sf[nt][r] <= mrun[r] + 8.f);
        if (!__all(ok)) {                      // rare: full max-reduce + rescale
            float mt[4];
            #pragma unroll
            for (int r = 0; r < 4; ++r)
                mt[r] = fmaxf(fmaxf(sf[0][r], sf[1][r]), fmaxf(sf[2][r], sf[3][r]));
            #pragma unroll
            for (int d = 1; d < 16; d <<= 1)
                #pragma unroll
                for (int r = 0; r < 4; ++r)
                    mt[r] = fmaxf(mt[r], __shfl_xor(mt[r], d));
            #pragma unroll
            for (int r = 0; r < 4; ++r) {
                const float mn = fmaxf(mrun[r], mt[r]);
                const float corr = __expf(mrun[r] - mn);
                mrun[r] = mn;
                lpart[r] *= corr;
                #pragma unroll
                for (int nt = 0; nt < 4; ++nt) oacc[nt][r] *= corr;
            }
        }

        // P = exp(S - m): per-lane l accumulation, bf16 P to LDS
        #pragma unroll
        for (int nt = 0; nt < 4; ++nt)
            #pragma unroll
            for (int r = 0; r < 4; ++r) {
                const float p = __expf(sf[nt][r] - mrun[r]);
                lpart[r] += p;
                *(ushort*)((char*)pls[w] + swzb(g*4 + r, (nt*16 + ln)*2)) = f2bf(p);
            }

        // O += P V
        __builtin_amdgcn_s_setprio(1);
        #pragma unroll
        for (int ks = 0; ks < 2; ++ks) {
            const short8 pa = *(const short8*)((const char*)pls[w] +
                                 swzb(ln, ks*64 + g*16));
            #pragma unroll
            for (int nt = 0; nt < 4; ++nt) {
                const short8 bv = *(const short8*)((const char*)vtls[cur] +
                                     swzb(nt*16 + ln, ks*64 + g*16));
                oacc[nt] = __builtin_amdgcn_mfma_f32_16x16x32_bf16(pa, bv, oacc[nt], 0,0,0);
            }
        }
        __builtin_amdgcn_s_setprio(0);
    }
    #undef STAGE

    // epilogue: one l butterfly, write bf16 partials + fp32 (m,l)
    #pragma unroll
    for (int d = 1; d < 16; d <<= 1)
        #pragma unroll
        for (int r = 0; r < 4; ++r)
            lpart[r] += __shfl_xor(lpart[r], d);

    const long pbase = (long)pid * 4096;
    #pragma unroll
    for (int nt = 0; nt < 4; ++nt)
        #pragma unroll
        for (int r = 0; r < 4; ++r)
            part_o[pbase + (w*16 + g*4 + r)*64 + nt*16 + ln] = f2bf(oacc[nt][r]);
    if (ln == 0)
        #pragma unroll
        for (int r = 0; r < 4; ++r) {
            part_ml[(long)pid*128 + (w*16 + g*4 + r)*2 + 0] = mrun[r];
            part_ml[(long)pid*128 + (w*16 + g*4 + r)*2 + 1] = lpart[r];
        }
}

// ---------------------------------------------------------------------------
// Merge <=8 chunk partials per q-row (LSE), normalize, write fp32 output.
// grid = 256 (b*64+qt), 256 thr.
// ---------------------------------------------------------------------------
__global__ __launch_bounds__(256) void attn_merge(
    const ushort* __restrict__ part_o, const float* __restrict__ part_ml,
    float* __restrict__ out)
{
    const int bid = blockIdx.x;
    const int b = bid >> 6, qt = bid & 63;
    const int t = threadIdx.x, row = t >> 2, sub = t & 3;
    const int nseg = (qt >> 3) + 1;
    const int base = b*CPB + chunk_prefix(qt);

    float ms[CHUNK], ls[CHUNK];
    float mstar = -INFINITY;
    for (int s = 0; s < nseg; ++s) {
        ms[s] = part_ml[(long)(base+s)*128 + row*2 + 0];
        ls[s] = part_ml[(long)(base+s)*128 + row*2 + 1];
        mstar = fmaxf(mstar, ms[s]);
    }
    float acc[16];
    #pragma unroll
    for (int i = 0; i < 16; ++i) acc[i] = 0.f;
    float lsum = 0.f;
    for (int s = 0; s < nseg; ++s) {
        const float wgt = __expf(ms[s] - mstar);
        lsum += ls[s] * wgt;
        const short8* po = (const short8*)(part_o + (long)(base+s)*4096 + row*64 + sub*16);
        #pragma unroll
        for (int j = 0; j < 2; ++j) {
            const short8 v8 = po[j];
            #pragma unroll
            for (int e = 0; e < 8; ++e)
                acc[j*8+e] += wgt * bf2f((ushort)v8[e]);
        }
    }
    const float inv = 1.f / lsum;
    float* op = out + ((long)b*T + qt*64 + row)*64 + sub*16;
    #pragma unroll
    for (int j = 0; j < 4; ++j)
        ((float4*)op)[j] = make_float4(acc[4*j+0]*inv, acc[4*j+1]*inv,
                                       acc[4*j+2]*inv, acc[4*j+3]*inv);
}

// ---------------------------------------------------------------------------
extern "C" void kernel_launch(void* const* d_in, const int* in_sizes, int n_in,
                              void* d_out, int out_size, void* d_ws, size_t ws_size,
                              hipStream_t stream)
{
    const float* x  = (const float*)d_in[0];
    const float* Wk = (const float*)d_in[1];
    const float* Wq = (const float*)d_in[2];
    const float* Wv = (const float*)d_in[3];

    char* w8 = (char*)d_ws;
    ushort* qb      = (ushort*)(w8);                    // 2 MB
    ushort* kb      = (ushort*)(w8 + (2l<<20));         // 2 MB
    ushort* vt      = (ushort*)(w8 + (4l<<20));         // 2 MB
    ushort* Wt      = (ushort*)(w8 + (6l<<20));         // 96 KB
    ushort* part_o  = (ushort*)(w8 + (7l<<20));         // 1152*8KB = 9.44 MB
    float*  part_ml = (float*) (w8 + (17l<<20));        // 576 KB

    wtrans    <<<3,         256, 0, stream>>>(Wq, Wk, Wv, Wt);
    proj_mfma <<<BT/64,     256, 0, stream>>>(x, Wt, qb, kb, vt);
    attn_mfma <<<Bb*CPB,    256, 0, stream>>>(qb, kb, vt, part_o, part_ml);
    attn_merge<<<Bb*(T/64), 256, 0, stream>>>(part_o, part_ml, (float*)d_out);
}